// Round 8
// baseline (158.404 us; speedup 1.0000x reference)
//
#include <hip/hip_runtime.h>

#define PH 7
#define PW 7

__device__ __forceinline__ float4 max4(float4 a, float4 b) {
    float4 r;
    r.x = fmaxf(a.x, b.x); r.y = fmaxf(a.y, b.y);
    r.z = fmaxf(a.z, b.z); r.w = fmaxf(a.w, b.w);
    return r;
}

// One block = one ROI (b, n); 512 threads = 8 waves.
// Waves 0..5 -> x-bin w = wv. Waves 6,7 split x-bin 6 (the wide one) in half,
// merged through LDS (one barrier). Lane t: x-parity px = t>>5 covers columns
// xi+0 / xi+1, channels c0 = (t&31)*4 (C == 128). The y-loop walks the FULL
// ROI height as one continuous pointer stream; h-accumulators are statically
// indexed via full unroll (registers, not scratch). No clamps in y (dy >= 2).
// Odd bin widths: last x-pair clamps px=1 to the same column -> same-address
// broadcast load, idempotent under max.
// Grid id = n*8 + b pins image b to XCD b (B==8); per-XCD dynamic block
// dispatch self-balances ROI-size variance.
__global__ __launch_bounds__(512, 8) void roi_maxpool_kernel(
    const float* __restrict__ feat,   // [B, 128, 128, 128]
    const int*   __restrict__ rois,   // [B, N, 4] = (minX, minY, maxX, maxY)
    float*       __restrict__ out,    // [B, N, PH, PW, 128]
    int N, int xcd_swizzle)
{
    const int X = 128, Y = 128, C = 128;

    const int id = blockIdx.x;
    int b, n;
    if (xcd_swizzle) { b = id & 7; n = id >> 3; }
    else             { b = id / N; n = id % N; }

    const int wv = threadIdx.x >> 6;   // wave 0..7
    const int t  = threadIdx.x & 63;
    const int px = t >> 5;             // x parity (0/1)
    const int c0 = (t & 31) * 4;       // 4 channels per lane

    const int4 roi = *reinterpret_cast<const int4*>(&rois[(b * N + n) * 4]);
    const int minX = roi.x, minY = roi.y, maxX = roi.z, maxY = roi.w;
    const int dx = (maxX - minX) / PW;   // >= 2 by construction
    const int dy = (maxY - minY) / PH;   // >= 2 by construction

    // Wave -> x-range [xs, xe) and the output x-bin it feeds.
    int xs, xe, w;
    if (wv < 6) {
        w = wv; xs = minX + wv * dx; xe = xs + dx;
    } else {
        w = 6;
        const int s6  = minX + 6 * dx;
        const int mid = s6 + ((maxX - s6 + 1) >> 1);
        xs = (wv == 6) ? s6 : mid;
        xe = (wv == 6) ? mid : maxX;
    }

    float4 acc[PH];
    #pragma unroll
    for (int h = 0; h < PH; ++h) { acc[h].x = acc[h].y = acc[h].z = acc[h].w = -INFINITY; }

    const float* base = feat + (long)b * X * Y * C + c0;
    for (int xi = xs; xi < xe; xi += 2) {
        int xl = xi + px; xl = (xl < xe) ? xl : (xe - 1);
        const float* p = base + (xl * Y + minY) * C;
        int ysh = minY;
        #pragma unroll
        for (int h = 0; h < PH; ++h) {
            const int yeh = (h == PH - 1) ? maxY : (ysh + dy);
            int cnt = yeh - ysh;                  // >= 2
            while (cnt >= 2) {
                const float4 v0 = *reinterpret_cast<const float4*>(p);
                const float4 v1 = *reinterpret_cast<const float4*>(p + C);
                p += 2 * C; cnt -= 2;
                acc[h] = max4(acc[h], max4(v0, v1));
            }
            if (cnt) {
                const float4 v0 = *reinterpret_cast<const float4*>(p);
                p += C;
                acc[h] = max4(acc[h], v0);
            }
            ysh = yeh;
        }
    }

    // Merge the two x-parity halves (lane t <-> t^32 hold the same channels).
    #pragma unroll
    for (int h = 0; h < PH; ++h) {
        acc[h].x = fmaxf(acc[h].x, __shfl_xor(acc[h].x, 32));
        acc[h].y = fmaxf(acc[h].y, __shfl_xor(acc[h].y, 32));
        acc[h].z = fmaxf(acc[h].z, __shfl_xor(acc[h].z, 32));
        acc[h].w = fmaxf(acc[h].w, __shfl_xor(acc[h].w, 32));
    }

    // Cross-wave merge for bin 6 (waves 6 and 7) through LDS.
    __shared__ float lds[PH * 128];
    if (wv == 7 && t < 32) {
        #pragma unroll
        for (int h = 0; h < PH; ++h)
            *reinterpret_cast<float4*>(&lds[h * 128 + c0]) = acc[h];
    }
    __syncthreads();

    if (t < 32 && wv <= 6) {
        if (wv == 6) {
            #pragma unroll
            for (int h = 0; h < PH; ++h)
                acc[h] = max4(acc[h], *reinterpret_cast<const float4*>(&lds[h * 128 + c0]));
        }
        #pragma unroll
        for (int h = 0; h < PH; ++h) {
            const long o = ((((long)b * N + n) * PH + h) * PW + w) * C + c0;
            *reinterpret_cast<float4*>(&out[o]) = acc[h];
        }
    }
}

extern "C" void kernel_launch(void* const* d_in, const int* in_sizes, int n_in,
                              void* d_out, int out_size, void* d_ws, size_t ws_size,
                              hipStream_t stream) {
    const float* feat = (const float*)d_in[0];
    const int*   rois = (const int*)d_in[1];
    float*       out  = (float*)d_out;

    // Shapes per setup_inputs(): B=8, X=Y=C=128, N=128.
    const int X = 128, Y = 128, C = 128;
    const int B = in_sizes[0] / (X * Y * C);
    const int N = in_sizes[1] / (4 * B);

    const int swz = (B == 8) ? 1 : 0;
    dim3 grid(B * N);
    roi_maxpool_kernel<<<grid, 512, 0, stream>>>(feat, rois, out, N, swz);
}

// Round 10
// 134.008 us; speedup vs baseline: 1.1820x; 1.1820x over previous
//
#include <hip/hip_runtime.h>

#define PH 7
#define PW 7
#define BINS (PH * PW)   // 49

__device__ __forceinline__ float4 max4(float4 a, float4 b) {
    float4 r;
    r.x = fmaxf(a.x, b.x); r.y = fmaxf(a.y, b.y);
    r.z = fmaxf(a.z, b.z); r.w = fmaxf(a.w, b.w);
    return r;
}

// One block = one wave = one output bin (b, n, h, w). Lane t: row-in-pair
// pp = t>>5, channels c0 = (t&31)*4 (C == 128). Each wave-load covers 2
// adjacent y-rows x 512B = 1KB. ALL raggedness is wave-uniform (H, W are
// uniform per bin): P = H>>1 pair-loads per column, one remainder pair by
// uniform branch, and (H odd) one same-address last-row load (512B broadcast,
// idempotent under max). No per-lane clamps -> ~zero duplicate load traffic
// (R5's always-on clamped epilogue was ~50% duplicates).
// Main loop: 2 columns x 2 pair-loads = 4 independent 1KB loads in flight.
// Grid: (id & 7) == b pins image b to XCD b; consecutive ids are the 49 bins
// of one ROI -> temporally-close same-XCD dispatch -> L2 reuse.
__global__ __launch_bounds__(64) void roi_maxpool_kernel(
    const float* __restrict__ feat,   // [B, 128, 128, 128]
    const int*   __restrict__ rois,   // [B, N, 4] = (minX, minY, maxX, maxY)
    float*       __restrict__ out,    // [B, N, PH, PW, 128]
    int N, int xcd_swizzle)
{
    const int X = 128, Y = 128, C = 128;

    const int id = blockIdx.x;
    int b, rest;
    if (xcd_swizzle) { b = id & 7; rest = id >> 3; }
    else             { b = id / (N * BINS); rest = id % (N * BINS); }
    const int n  = rest / BINS;
    const int hw = rest % BINS;
    const int w  = hw % PW;           // x-bin
    const int h  = hw / PW;           // y-bin

    const int4 roi = *reinterpret_cast<const int4*>(&rois[(b * N + n) * 4]);
    const int minX = roi.x, minY = roi.y, maxX = roi.z, maxY = roi.w;
    const int dx = (maxX - minX) / PW;   // >= 2
    const int dy = (maxY - minY) / PH;   // >= 2

    // Bin k covers [lo+k*d, lo+(k+1)*d); last bin extends to hi.
    const int xs = minX + w * dx;
    const int xe = (w == PW - 1) ? maxX : (xs + dx);
    const int ys = minY + h * dy;
    const int ye = (h == PH - 1) ? maxY : (ys + dy);

    const int t  = threadIdx.x;       // 0..63
    const int pp = t >> 5;            // row-in-pair (0/1)
    const int c0 = (t & 31) * 4;      // 4 channels per lane

    const int H   = ye - ys;          // >= 2, wave-uniform
    const int P   = H >> 1;           // pair-loads per column, >= 1
    const int odd = H & 1;

    const int colStride = Y * C;      // floats per x-column
    const float* base = feat + b * X * Y * C + c0;   // fits 32-bit math

    float4 m; m.x = m.y = m.z = m.w = -INFINITY;

    int xi = xs;
    // Column pairs: 2 columns x 2 pair-loads = 4 loads in flight.
    for (; xi + 1 < xe; xi += 2) {
        const float* p0 = base + (xi * Y + ys + pp) * C;
        const float* p1 = p0 + colStride;
        int k = P;
        for (; k >= 2; k -= 2) {
            const float4 v0 = *reinterpret_cast<const float4*>(p0);
            const float4 v1 = *reinterpret_cast<const float4*>(p0 + 2 * C);
            const float4 v2 = *reinterpret_cast<const float4*>(p1);
            const float4 v3 = *reinterpret_cast<const float4*>(p1 + 2 * C);
            p0 += 4 * C; p1 += 4 * C;
            m = max4(m, max4(max4(v0, v1), max4(v2, v3)));
        }
        if (k) {   // uniform remainder pair (1 pair-load per column)
            const float4 v0 = *reinterpret_cast<const float4*>(p0);
            const float4 v1 = *reinterpret_cast<const float4*>(p1);
            p0 += 2 * C; p1 += 2 * C;
            m = max4(m, max4(v0, v1));
        }
        if (odd) { // last row: all lanes read the same 512B row (broadcast)
            const float* q0 = base + (xi * Y + (ye - 1)) * C;
            const float4 v0 = *reinterpret_cast<const float4*>(q0);
            const float4 v1 = *reinterpret_cast<const float4*>(q0 + colStride);
            m = max4(m, max4(v0, v1));
        }
    }
    if (xi < xe) {  // solo last column (odd bin width)
        const float* p0 = base + (xi * Y + ys + pp) * C;
        int k = P;
        for (; k >= 2; k -= 2) {
            const float4 v0 = *reinterpret_cast<const float4*>(p0);
            const float4 v1 = *reinterpret_cast<const float4*>(p0 + 2 * C);
            p0 += 4 * C;
            m = max4(m, max4(v0, v1));
        }
        if (k) {
            const float4 v0 = *reinterpret_cast<const float4*>(p0);
            p0 += 2 * C;
            m = max4(m, v0);
        }
        if (odd) {
            const float4 v0 = *reinterpret_cast<const float4*>(base + (xi * Y + (ye - 1)) * C);
            m = max4(m, v0);
        }
    }

    // Merge the two row-parity halves (lane t <-> t^32 hold the same channels).
    m.x = fmaxf(m.x, __shfl_xor(m.x, 32));
    m.y = fmaxf(m.y, __shfl_xor(m.y, 32));
    m.z = fmaxf(m.z, __shfl_xor(m.z, 32));
    m.w = fmaxf(m.w, __shfl_xor(m.w, 32));

    if (t < 32) {
        const int oidx = (((b * N + n) * PH + h) * PW + w) * C + c0;
        *reinterpret_cast<float4*>(&out[oidx]) = m;
    }
}

extern "C" void kernel_launch(void* const* d_in, const int* in_sizes, int n_in,
                              void* d_out, int out_size, void* d_ws, size_t ws_size,
                              hipStream_t stream) {
    const float* feat = (const float*)d_in[0];
    const int*   rois = (const int*)d_in[1];
    float*       out  = (float*)d_out;

    // Shapes per setup_inputs(): B=8, X=Y=C=128, N=128.
    const int X = 128, Y = 128, C = 128;
    const int B = in_sizes[0] / (X * Y * C);
    const int N = in_sizes[1] / (4 * B);

    const int swz = (B == 8) ? 1 : 0;
    dim3 grid(B * N * BINS);
    roi_maxpool_kernel<<<grid, 64, 0, stream>>>(feat, rois, out, N, swz);
}

// Round 11
// 131.280 us; speedup vs baseline: 1.2066x; 1.0208x over previous
//
#include <hip/hip_runtime.h>

#define PH 7
#define PW 7
#define BINS (PH * PW)   // 49

__device__ __forceinline__ float4 max4(float4 a, float4 b) {
    float4 r;
    r.x = fmaxf(a.x, b.x); r.y = fmaxf(a.y, b.y);
    r.z = fmaxf(a.z, b.z); r.w = fmaxf(a.w, b.w);
    return r;
}

// One block = one wave = one output bin (b, n, h, w). Lane t: row-in-pair
// pp = t>>5, channels c0 = (t&31)*4 (C == 128). Each 1KB wave-load covers
// 2 adjacent y-rows (x-col fixed).
// The bin's pair-tiles are FLATTENED: j in [0, W*P), col = (j*magic)>>16,
// pair = j - col*P (exact for P<=4, j<=36; all wave-uniform scalar math).
// Addresses are pure shifts: elem = (b<<21)+(x<<14)+(y<<7)+c. The flat loop
// is unrolled 8x into 8 independent accumulators + 8 in-flight loads (no
// register-reuse serialization -> ~8KB in flight per wave; R10 had VGPR=16
// and ~1 load slot). Tail via 4/2/1 stepdown (zero duplicate loads).
// Odd H: one broadcast-row pass per column (lanes share the 512B row).
// Grid: (id & 7) == b pins image b to XCD b (L2 locality, R2->R4 -60% FETCH).
__global__ __launch_bounds__(64) void roi_maxpool_kernel(
    const float* __restrict__ feat,   // [B, 128, 128, 128]
    const int*   __restrict__ rois,   // [B, N, 4] = (minX, minY, maxX, maxY)
    float*       __restrict__ out,    // [B, N, PH, PW, 128]
    int N, int xcd_swizzle)
{
    const int id = blockIdx.x;
    int b, rest;
    if (xcd_swizzle) { b = id & 7; rest = id >> 3; }
    else             { b = id / (N * BINS); rest = id % (N * BINS); }
    const int n  = rest / BINS;
    const int hw = rest % BINS;
    const int w  = hw % PW;           // x-bin
    const int h  = hw / PW;           // y-bin

    const int4 roi = *reinterpret_cast<const int4*>(&rois[(b * N + n) * 4]);
    const int minX = roi.x, minY = roi.y, maxX = roi.z, maxY = roi.w;
    const int dx = (maxX - minX) / PW;   // >= 2
    const int dy = (maxY - minY) / PH;   // >= 2

    // Bin k covers [lo+k*d, lo+(k+1)*d); last bin extends to hi.
    const int xs = minX + w * dx;
    const int xe = (w == PW - 1) ? maxX : (xs + dx);
    const int ys = minY + h * dy;
    const int ye = (h == PH - 1) ? maxY : (ys + dy);

    const int t  = threadIdx.x;       // 0..63
    const int pp = t >> 5;            // row-in-pair (0/1)
    const int c0 = (t & 31) * 4;      // 4 channels per lane

    const int W   = xe - xs;          // wave-uniform, >= 2
    const int H   = ye - ys;          // wave-uniform, >= 2
    const int P   = H >> 1;           // pair-tiles per column, 1..4(+)
    const int odd = H & 1;
    const int T   = W * P;            // total pair-tiles, >= 2
    const unsigned magic = (65536u + (unsigned)P - 1u) / (unsigned)P;

    // elem index = (b<<21) + (x<<14) + (y<<7) + c  (X=Y=C=128)
    const float* bp = feat + (b << 21) + (xs << 14) + ((ys + pp) << 7) + c0;

    float4 acc[8];
    #pragma unroll
    for (int u = 0; u < 8; ++u) { acc[u].x = acc[u].y = acc[u].z = acc[u].w = -INFINITY; }

    int j = 0;
    for (; j + 8 <= T; j += 8) {
        #pragma unroll
        for (int u = 0; u < 8; ++u) {
            const unsigned jj = (unsigned)(j + u);
            const int col  = (int)((jj * magic) >> 16);
            const int pair = (int)jj - col * P;
            const float4 v = *reinterpret_cast<const float4*>(bp + (col << 14) + (pair << 8));
            acc[u] = max4(acc[u], v);
        }
    }
    if (j + 4 <= T) {
        #pragma unroll
        for (int u = 0; u < 4; ++u) {
            const unsigned jj = (unsigned)(j + u);
            const int col  = (int)((jj * magic) >> 16);
            const int pair = (int)jj - col * P;
            const float4 v = *reinterpret_cast<const float4*>(bp + (col << 14) + (pair << 8));
            acc[u] = max4(acc[u], v);
        }
        j += 4;
    }
    if (j + 2 <= T) {
        #pragma unroll
        for (int u = 0; u < 2; ++u) {
            const unsigned jj = (unsigned)(j + u);
            const int col  = (int)((jj * magic) >> 16);
            const int pair = (int)jj - col * P;
            const float4 v = *reinterpret_cast<const float4*>(bp + (col << 14) + (pair << 8));
            acc[u] = max4(acc[u], v);
        }
        j += 2;
    }
    if (j < T) {
        const unsigned jj = (unsigned)j;
        const int col  = (int)((jj * magic) >> 16);
        const int pair = (int)jj - col * P;
        const float4 v = *reinterpret_cast<const float4*>(bp + (col << 14) + (pair << 8));
        acc[0] = max4(acc[0], v);
    }

    if (odd) {  // last y-row: all lanes read the same 512B row (broadcast)
        const float* bo = feat + (b << 21) + (xs << 14) + ((ye - 1) << 7) + c0;
        int ci = 0;
        for (; ci + 4 <= W; ci += 4) {
            #pragma unroll
            for (int u = 0; u < 4; ++u) {
                const float4 v = *reinterpret_cast<const float4*>(bo + ((ci + u) << 14));
                acc[u + 4] = max4(acc[u + 4], v);
            }
        }
        if (ci + 2 <= W) {
            #pragma unroll
            for (int u = 0; u < 2; ++u) {
                const float4 v = *reinterpret_cast<const float4*>(bo + ((ci + u) << 14));
                acc[u + 4] = max4(acc[u + 4], v);
            }
            ci += 2;
        }
        if (ci < W) {
            const float4 v = *reinterpret_cast<const float4*>(bo + (ci << 14));
            acc[4] = max4(acc[4], v);
        }
    }

    float4 m = max4(max4(max4(acc[0], acc[1]), max4(acc[2], acc[3])),
                    max4(max4(acc[4], acc[5]), max4(acc[6], acc[7])));

    // Merge the two row-parity halves (lane t <-> t^32 hold the same channels).
    m.x = fmaxf(m.x, __shfl_xor(m.x, 32));
    m.y = fmaxf(m.y, __shfl_xor(m.y, 32));
    m.z = fmaxf(m.z, __shfl_xor(m.z, 32));
    m.w = fmaxf(m.w, __shfl_xor(m.w, 32));

    if (t < 32) {
        const int oidx = (((b * N + n) * PH + h) * PW + w) * 128 + c0;
        *reinterpret_cast<float4*>(&out[oidx]) = m;
    }
}

extern "C" void kernel_launch(void* const* d_in, const int* in_sizes, int n_in,
                              void* d_out, int out_size, void* d_ws, size_t ws_size,
                              hipStream_t stream) {
    const float* feat = (const float*)d_in[0];
    const int*   rois = (const int*)d_in[1];
    float*       out  = (float*)d_out;

    // Shapes per setup_inputs(): B=8, X=Y=C=128, N=128.
    const int X = 128, Y = 128, C = 128;
    const int B = in_sizes[0] / (X * Y * C);
    const int N = in_sizes[1] / (4 * B);

    const int swz = (B == 8) ? 1 : 0;
    dim3 grid(B * N * BINS);
    roi_maxpool_kernel<<<grid, 64, 0, stream>>>(feat, rois, out, N, swz);
}